// Round 4
// baseline (148.820 us; speedup 1.0000x reference)
//
#include <hip/hip_runtime.h>

#define T_LEN   1048576
#define K1B     1024                // K1 blocks, 1024 elems each
#define BLK     256
#define SEG     256                 // rows per output block
#define NSEG    (T_LEN / SEG)       // 4096 segments
#define MAXO    25
#define CLAMP_HI 24.0f
#define BIGF    1e30f

typedef float f4v __attribute__((ext_vector_type(4)));

// Saturating-add function f(c) = min(max(c + a, l), h); closed under composition.
struct Trip { float a, l, h; };

__device__ __forceinline__ Trip comb(Trip x, Trip y) {   // apply x first, then y
    Trip r;
    r.a = x.a + y.a;
    r.l = fmaxf(x.l + y.a, y.l);
    r.h = fminf(fmaxf(x.h + y.a, y.l), y.h);
    return r;
}
__device__ __forceinline__ float applyT(Trip p, float c) {
    return fminf(fmaxf(c + p.a, p.l), p.h);
}
__device__ __forceinline__ Trip shflUpTrip(Trip v, int off) {
    Trip r;
    r.a = __shfl_up(v.a, off, 64);
    r.l = __shfl_up(v.l, off, 64);
    r.h = __shfl_up(v.h, off, 64);
    return r;
}

// ---- K1: per-segment triples; last-arriving block scans ALL 4096 of them ----
__global__ __launch_bounds__(BLK)
void k1_fused(const int* __restrict__ seq, const float* __restrict__ delta,
              float* __restrict__ tri, float* __restrict__ entry,
              int* __restrict__ cnt) {
    __shared__ float dl[16];
    __shared__ int isLast;
    __shared__ Trip agg[4];
    const int tid = threadIdx.x, lane = tid & 63, wid = tid >> 6;
    const int bid = blockIdx.x;

    if (tid < 16) dl[tid] = delta[tid];
    __syncthreads();

    const int4 s4 = *(const int4*)(seq + bid * 1024 + tid * 4);
    Trip t = {dl[s4.x], 0.0f, CLAMP_HI};
    { Trip e = {dl[s4.y], 0.0f, CLAMP_HI}; t = comb(t, e); }
    { Trip e = {dl[s4.z], 0.0f, CLAMP_HI}; t = comb(t, e); }
    { Trip e = {dl[s4.w], 0.0f, CLAMP_HI}; t = comb(t, e); }

#pragma unroll
    for (int off = 1; off < 64; off <<= 1) {
        Trip o = shflUpTrip(t, off);
        if (lane >= off) t = comb(o, t);
    }
    if (lane == 63) {                       // wave = one 256-elem segment
        const int sid = bid * 4 + wid;
        tri[3 * sid + 0] = t.a;
        tri[3 * sid + 1] = t.l;
        tri[3 * sid + 2] = t.h;
    }
    __syncthreads();
    if (tid == 0) {
        __threadfence();                    // release: triples visible device-wide
        isLast = (atomicAdd(cnt, 1) == K1B - 1);
    }
    __syncthreads();
    if (!isLast) return;

    // ---- last block: scan all NSEG=4096 triples, 16 per thread ----
    __threadfence();                        // acquire
    f4v f[12];                              // 16 triples = 48 floats = 12 float4
    const f4v* p = (const f4v*)(tri + tid * 48);
#pragma unroll
    for (int i = 0; i < 12; ++i) f[i] = p[i];
    const float* fp = (const float*)f;

    Trip loc[16];
#pragma unroll
    for (int k = 0; k < 16; ++k)
        loc[k] = {fp[3 * k], fp[3 * k + 1], fp[3 * k + 2]};

    Trip incl = loc[0];
#pragma unroll
    for (int k = 1; k < 16; ++k) incl = comb(incl, loc[k]);

#pragma unroll
    for (int off = 1; off < 64; off <<= 1) {
        Trip o = shflUpTrip(incl, off);
        if (lane >= off) incl = comb(o, incl);
    }
    if (lane == 63) agg[wid] = incl;
    __syncthreads();

    Trip W = {0.0f, -BIGF, BIGF};                    // identity
    for (int w = 0; w < wid; ++w) W = comb(W, agg[w]);
    const Trip prev = shflUpTrip(incl, 1);
    const Trip E = (lane == 0) ? W : comb(W, prev);  // exclusive prefix of 16-groups

    float ebuf[16];
    float c = applyT(E, 0.0f);
    ebuf[0] = c;
#pragma unroll
    for (int k = 0; k < 15; ++k) { c = applyT(loc[k], c); ebuf[k + 1] = c; }

    f4v* ep = (f4v*)(entry + 16 * tid);
#pragma unroll
    for (int i = 0; i < 4; ++i)
        ep[i] = ((const f4v*)ebuf)[i];
}

// ---- K2: per-row softmax, single exp pass, nontemporal float4 writes -------
__global__ __launch_bounds__(BLK)
void k2_out(const int* __restrict__ seq, const float* __restrict__ delta,
            const float* __restrict__ bias, const float* __restrict__ scale,
            const float* __restrict__ entry, float* __restrict__ out) {
    __shared__ __align__(16) float tile[SEG * MAXO];     // 25600 B
    __shared__ Trip agg[4];
    __shared__ float dl[16], bs[MAXO];

    const int tid = threadIdx.x, lane = tid & 63, wid = tid >> 6;
    const int bid = blockIdx.x;

    if (tid < 16)   dl[tid] = delta[tid];
    if (tid < MAXO) bs[tid] = bias[tid];
    const float sfac = scale[0];
    const float cseg = entry[bid];                       // broadcast load
    const int s = seq[bid * SEG + tid];
    __syncthreads();

    Trip t = {dl[s], 0.0f, CLAMP_HI};
#pragma unroll
    for (int off = 1; off < 64; off <<= 1) {
        Trip o = shflUpTrip(t, off);
        if (lane >= off) t = comb(o, t);
    }
    if (lane == 63) agg[wid] = t;
    __syncthreads();

    float cb = cseg;
    for (int w = 0; w < wid; ++w) cb = applyT(agg[w], cb);
    const float c = applyT(t, cb);                       // counter for row tid

    // softmax without max-subtraction (logits <= ~0.4, fp32 safe)
    float ev[MAXO];
    float sum = 0.0f;
#pragma unroll
    for (int j = 0; j < MAXO; ++j) {
        ev[j] = __expf(fmaf(-sfac, fabsf((float)j - c), bs[j]));
        sum += ev[j];
    }
    const float r = 1.0f / sum;
#pragma unroll
    for (int j = 0; j < MAXO; ++j)                       // stride-25: conflict-free
        tile[tid * MAXO + j] = ev[j] * r;
    __syncthreads();

    const f4v* tp = (const f4v*)tile;
    f4v* op = (f4v*)(out + (size_t)bid * SEG * MAXO);
#pragma unroll 4
    for (int i = tid; i < SEG * MAXO / 4; i += BLK)      // 1600 float4s
        __builtin_nontemporal_store(tp[i], op + i);
}

extern "C" void kernel_launch(void* const* d_in, const int* in_sizes, int n_in,
                              void* d_out, int out_size, void* d_ws, size_t ws_size,
                              hipStream_t stream) {
    const int*   seq   = (const int*)d_in[0];
    const float* delta = (const float*)d_in[1];
    const float* bias  = (const float*)d_in[2];
    const float* scale = (const float*)d_in[3];
    float* out = (float*)d_out;

    float* tri   = (float*)d_ws;                 // NSEG*3 floats = 48 KB
    float* entry = tri + NSEG * 3;               // NSEG floats   = 16 KB
    int*   cnt   = (int*)(entry + NSEG);         // 4 bytes

    hipMemsetAsync(cnt, 0, sizeof(int), stream); // ws is poisoned 0xAA each call

    k1_fused<<<K1B, BLK, 0, stream>>>(seq, delta, tri, entry, cnt);
    k2_out  <<<NSEG, BLK, 0, stream>>>(seq, delta, bias, scale, entry, out);
}